// Round 5
// baseline (932.920 us; speedup 1.0000x reference)
//
#include <hip/hip_runtime.h>
#include <hip/hip_bf16.h>

// Problem constants
#define B_DIM   512
#define IN_DIM  4096
#define OUT_DIM 11008

typedef __bf16 bf16x4 __attribute__((ext_vector_type(4)));
typedef __bf16 bf16x8 __attribute__((ext_vector_type(8)));
typedef float  floatx4 __attribute__((ext_vector_type(4)));

// ---------------------------------------------------------------------------
// Pass 1: x fp32 -> bf16 (tiny: 12 MB traffic, ~2 us)
// ---------------------------------------------------------------------------
__global__ __launch_bounds__(256) void conv_x_kernel(
    const float* __restrict__ x, __bf16* __restrict__ xb) {
  int idx = blockIdx.x * blockDim.x + threadIdx.x;  // quad index
  float4 v = ((const float4*)x)[idx];
  bf16x4 o;
  o[0] = (__bf16)v.x; o[1] = (__bf16)v.y; o[2] = (__bf16)v.z; o[3] = (__bf16)v.w;
  ((bf16x4*)xb)[idx] = o;
}

// ---------------------------------------------------------------------------
// Pass 2: fused QINS-decode + GEMM, v5.
// Key insight: the mfma_16x16x32 B-fragment is, per lane, 8 CONTIGUOUS
// k-elements of one output row — exactly the row-major layout of
// stored/sign. So B is loaded global->register and decoded in-register:
// NO sB in LDS, no ds_write, no extra barrier, no hand-counted vmcnt.
// Remaining structure is the round-0-proven m97 skeleton:
//  - sA double-buffered via global_load_lds + plain __syncthreads()
//    (compiler drains vmcnt before s_barrier -> correctness guaranteed)
//  - B prefetched 1 tile ahead in plain C++ loads (compiler-managed waits)
//  - __launch_bounds__(256,3): 16 KB LDS -> 3 blocks/CU -> all 688 blocks
//    co-resident (v2/v3 were capped at 2 -> 1.34-round makespan)
// Decode numerics: exp via fma (contraction-equivalent to prior rounds);
// sign applied as sign-bit XOR (bit-exact to multiplying by +-1).
// ---------------------------------------------------------------------------
__device__ __forceinline__ void gl_lds16(const __bf16* g, __bf16* l) {
  __builtin_amdgcn_global_load_lds(
      (const __attribute__((address_space(1))) void*)g,
      (__attribute__((address_space(3))) void*)l, 16, 0, 0);
}

// w = sign * exp(lmin + (255 - s)/254 * (lmax - lmin))
__device__ __forceinline__ float dec1f(int s, int g, float lmin, float slope) {
  float e = __expf(fmaf((float)(255 - s), slope, lmin));
  return __uint_as_float(__float_as_uint(e) ^ ((unsigned)g & 0x80000000u));
}

__device__ __forceinline__ bf16x8 dec8(int4 sl, int4 sh, int4 gl, int4 gh,
                                       float lmin, float slope) {
  bf16x8 w;
  w[0] = (__bf16)dec1f(sl.x, gl.x, lmin, slope);
  w[1] = (__bf16)dec1f(sl.y, gl.y, lmin, slope);
  w[2] = (__bf16)dec1f(sl.z, gl.z, lmin, slope);
  w[3] = (__bf16)dec1f(sl.w, gl.w, lmin, slope);
  w[4] = (__bf16)dec1f(sh.x, gh.x, lmin, slope);
  w[5] = (__bf16)dec1f(sh.y, gh.y, lmin, slope);
  w[6] = (__bf16)dec1f(sh.z, gh.z, lmin, slope);
  w[7] = (__bf16)dec1f(sh.w, gh.w, lmin, slope);
  return w;
}

__global__ __launch_bounds__(256, 3) void fused_qins_gemm_kernel(
    const __bf16* __restrict__ A,      // 512 x 4096 bf16 (pre-converted x)
    const int* __restrict__ stored,    // 11008 x 4096 int32 in [1,255]
    const int* __restrict__ sign,      // 11008 x 4096 int32 +-1
    const float* __restrict__ logmin, const float* __restrict__ logmax,
    const float* __restrict__ scale, const float* __restrict__ bias,
    float* __restrict__ out) {
  constexpr int K = IN_DIM, N = OUT_DIM;
  constexpr int BK = 32;
  constexpr int NIT = K / BK;          // 128 k-tiles

  __shared__ __align__(16) __bf16 sA[2][128 * BK];  // 2 x 8 KB = 16 KB total

  const int tid  = threadIdx.x;
  const int lane = tid & 63;
  const int wave = tid >> 6;
  const int wm   = (wave >> 1) * 64;   // wave M offset (0/64)
  const int wn   = (wave & 1) * 32;    // wave N offset (0/32)
  const int m16  = lane & 15;
  const int q    = lane >> 4;          // 0..3

  // XCD-grouped swizzle: 688 = 8 XCDs x 86; bm fastest so the 4 blocks
  // sharing a bn panel co-reside on one XCD (stored/sign reuse hits L2).
  const int wg  = blockIdx.x;                 // 0..687
  const int g   = (wg & 7) * 86 + (wg >> 3);  // bijective
  const int bm0 = (g & 3) * 128;              // 4 M-tiles
  const int bn0 = (g >> 2) * 64;              // 172 N-tiles

  const float lmin  = logmin[0];
  const float slope = (logmax[0] - lmin) * (1.0f / 254.0f);

  // A staging (round-0-proven linear layout): row r0, k-chunk (tid&3)*8
  const int r0 = tid >> 2;
  const int c0 = (tid & 3) * 8;
  const __bf16* gA0 = A + (size_t)(bm0 + r0) * K + c0;
  const __bf16* gA1 = A + (size_t)(bm0 + r0 + 64) * K + c0;

  // B direct-fragment pointers: lane covers rows rB0, rB0+16 at k = kt + q*8
  const int rB0 = bn0 + wn + m16;
  const int* bS0 = stored + (size_t)rB0 * K + q * 8;
  const int* bS1 = bS0 + 16 * K;
  const int* bG0 = sign + (size_t)rB0 * K + q * 8;
  const int* bG1 = bG0 + 16 * K;

  floatx4 acc[4][2] = {};

  // Prologue: A(0) -> sA[0] (async), B(0) -> reg set a.
  gl_lds16(gA0, &sA[0][tid * 8]);
  gl_lds16(gA1, &sA[0][2048 + tid * 8]);
  int4 as0 = *(const int4*)(bS0),     as1 = *(const int4*)(bS0 + 4);
  int4 as2 = *(const int4*)(bS1),     as3 = *(const int4*)(bS1 + 4);
  int4 ag0 = *(const int4*)(bG0),     ag1 = *(const int4*)(bG0 + 4);
  int4 ag2 = *(const int4*)(bG1),     ag3 = *(const int4*)(bG1 + 4);
  int4 bs0, bs1, bs2, bs3, bg0, bg1, bg2, bg3;  // reg set b

  // BODY(t): __syncthreads (drains vmcnt -> A(t) landed, old-buffer readers
  // done) -> issue A(t+1) -> ds_read afr(t) -> issue B(t+1) into other reg
  // set -> decode B(t) (overlaps ds_read latency) -> 8 MFMA.
#define BODY(T, CUR, NXT, S0, S1, S2, S3, G0, G1, G2, G3,                     \
             T0, T1, T2, T3, U0, U1, U2, U3)                                  \
  {                                                                           \
    __syncthreads();                                                          \
    const int ktn = ((T) + 1 < NIT) ? ((T) + 1) * BK : 0;                     \
    if ((T) + 1 < NIT) {                                                      \
      gl_lds16(gA0 + ktn, &sA[NXT][tid * 8]);                                 \
      gl_lds16(gA1 + ktn, &sA[NXT][2048 + tid * 8]);                          \
    }                                                                         \
    bf16x8 afr[4];                                                            \
    _Pragma("unroll")                                                         \
    for (int ii = 0; ii < 4; ++ii)                                            \
      afr[ii] = *(const bf16x8*)&sA[CUR][(wm + ii * 16 + m16) * BK + q * 8];  \
    T0 = *(const int4*)(bS0 + ktn); T1 = *(const int4*)(bS0 + ktn + 4);       \
    T2 = *(const int4*)(bS1 + ktn); T3 = *(const int4*)(bS1 + ktn + 4);       \
    U0 = *(const int4*)(bG0 + ktn); U1 = *(const int4*)(bG0 + ktn + 4);       \
    U2 = *(const int4*)(bG1 + ktn); U3 = *(const int4*)(bG1 + ktn + 4);       \
    bf16x8 bfr0 = dec8(S0, S1, G0, G1, lmin, slope);                          \
    bf16x8 bfr1 = dec8(S2, S3, G2, G3, lmin, slope);                          \
    _Pragma("unroll")                                                         \
    for (int mi = 0; mi < 4; ++mi) {                                          \
      acc[mi][0] = __builtin_amdgcn_mfma_f32_16x16x32_bf16(                   \
          afr[mi], bfr0, acc[mi][0], 0, 0, 0);                                \
      acc[mi][1] = __builtin_amdgcn_mfma_f32_16x16x32_bf16(                   \
          afr[mi], bfr1, acc[mi][1], 0, 0, 0);                                \
    }                                                                         \
  }

  for (int t = 0; t < NIT; t += 2) {
    BODY(t,     0, 1, as0, as1, as2, as3, ag0, ag1, ag2, ag3,
                      bs0, bs1, bs2, bs3, bg0, bg1, bg2, bg3);
    BODY(t + 1, 1, 0, bs0, bs1, bs2, bs3, bg0, bg1, bg2, bg3,
                      as0, as1, as2, as3, ag0, ag1, ag2, ag3);
  }
#undef BODY

  // Epilogue. C/D layout: col = lane&15, row = q*4 + reg  [m89]
#pragma unroll
  for (int ni = 0; ni < 2; ++ni) {
    const int col = bn0 + wn + ni * 16 + m16;
    const float sc = scale[col];
    const float bb = bias[col] * sc;
#pragma unroll
    for (int mi = 0; mi < 4; ++mi) {
#pragma unroll
      for (int r = 0; r < 4; ++r) {
        const int row = bm0 + wm + mi * 16 + q * 4 + r;
        out[row * N + col] = acc[mi][ni][r] * sc + bb;
      }
    }
  }
}

// ---------------------------------------------------------------------------
extern "C" void kernel_launch(void* const* d_in, const int* in_sizes, int n_in,
                              void* d_out, int out_size, void* d_ws, size_t ws_size,
                              hipStream_t stream) {
  const float* x      = (const float*)d_in[0];
  const int*   stored = (const int*)d_in[1];
  const int*   sign   = (const int*)d_in[2];
  const float* logmin = (const float*)d_in[3];
  const float* logmax = (const float*)d_in[4];
  const float* scale  = (const float*)d_in[5];
  const float* bias   = (const float*)d_in[6];
  float* out = (float*)d_out;

  __bf16* wsX = (__bf16*)d_ws;  // 512*4096 bf16 = 4 MB

  conv_x_kernel<<<2048, 256, 0, stream>>>(x, wsX);
  // 172 bn-tiles x 4 bm-tiles = 688 blocks (XCD-swizzled)
  fused_qins_gemm_kernel<<<688, 256, 0, stream>>>(
      wsX, stored, sign, logmin, logmax, scale, bias, out);
}

// Round 7
// 583.508 us; speedup vs baseline: 1.5988x; 1.5988x over previous
//
#include <hip/hip_runtime.h>
#include <hip/hip_bf16.h>

// Problem constants
#define B_DIM   512
#define IN_DIM  4096
#define OUT_DIM 11008

typedef __bf16 bf16x4 __attribute__((ext_vector_type(4)));
typedef __bf16 bf16x8 __attribute__((ext_vector_type(8)));
typedef float  floatx4 __attribute__((ext_vector_type(4)));

// ---------------------------------------------------------------------------
// Pass 1: x fp32 -> bf16 (tiny: 12 MB traffic, ~2 us)
// ---------------------------------------------------------------------------
__global__ __launch_bounds__(256) void conv_x_kernel(
    const float* __restrict__ x, __bf16* __restrict__ xb) {
  int idx = blockIdx.x * blockDim.x + threadIdx.x;  // quad index
  float4 v = ((const float4*)x)[idx];
  bf16x4 o;
  o[0] = (__bf16)v.x; o[1] = (__bf16)v.y; o[2] = (__bf16)v.z; o[3] = (__bf16)v.w;
  ((bf16x4*)xb)[idx] = o;
}

// ---------------------------------------------------------------------------
// Pass 2: fused QINS-decode + GEMM, v6 (resubmit — round-6 bench was an
// infra failure: container acquire failed, kernel never ran).
// Lessons applied (v2/v3: reg-dest loads drained at barriers; v4: hand-asm
// crash; v5: uncoalesced gather):
//  - ALL global traffic via global_load_lds (coalesced, issued a full tile
//    before the barrier that drains it — m97 invariant). Zero reg-dest
//    global loads in the K-loop. Zero inline asm. ONE __syncthreads/tile.
//  - Raw int32 stored/sign staged to LDS; decode AFTER ds_read, in-register,
//    feeding MFMA directly (no decoded-B ds_write, no second barrier).
//  - 1x4 wave layout (wave owns 16 N-cols x 128 M-rows): each B element
//    decoded once per block; B LDS reads not duplicated across waves.
//  - B LDS placement chunk-XOR (kc ^= row&7) applied on the GLOBAL source
//    (gl_lds dest must stay lane-linear): spreads b128 reads across all 32
//    banks (8 slots x 8 lanes = data floor) instead of 16-way conflicts.
//  - LDS 48 KB -> 3 blocks/CU; launch_bounds(256,3).
// ---------------------------------------------------------------------------
__device__ __forceinline__ void gl_lds16(const void* g, void* l) {
  __builtin_amdgcn_global_load_lds(
      (const __attribute__((address_space(1))) void*)g,
      (__attribute__((address_space(3))) void*)l, 16, 0, 0);
}

// w = sign * exp(lmin + (255 - s)/254 * (lmax - lmin))
// sign applied as sign-bit XOR (g = +1 -> bit31 0, g = -1 (0xFFFFFFFF) ->
// bit31 1) — verified bit-exact in v5 (passed).
__device__ __forceinline__ float dec1f(int s, int g, float lmin, float slope) {
  float e = __expf(fmaf((float)(255 - s), slope, lmin));
  return __uint_as_float(__float_as_uint(e) ^ ((unsigned)g & 0x80000000u));
}

__device__ __forceinline__ bf16x8 dec8(int4 sl, int4 sh, int4 gl, int4 gh,
                                       float lmin, float slope) {
  bf16x8 w;
  w[0] = (__bf16)dec1f(sl.x, gl.x, lmin, slope);
  w[1] = (__bf16)dec1f(sl.y, gl.y, lmin, slope);
  w[2] = (__bf16)dec1f(sl.z, gl.z, lmin, slope);
  w[3] = (__bf16)dec1f(sl.w, gl.w, lmin, slope);
  w[4] = (__bf16)dec1f(sh.x, gh.x, lmin, slope);
  w[5] = (__bf16)dec1f(sh.y, gh.y, lmin, slope);
  w[6] = (__bf16)dec1f(sh.z, gh.z, lmin, slope);
  w[7] = (__bf16)dec1f(sh.w, gh.w, lmin, slope);
  return w;
}

__global__ __launch_bounds__(256, 3) void fused_qins_gemm_kernel(
    const __bf16* __restrict__ A,      // 512 x 4096 bf16 (pre-converted x)
    const int* __restrict__ stored,    // 11008 x 4096 int32 in [1,255]
    const int* __restrict__ sign,      // 11008 x 4096 int32 +-1
    const float* __restrict__ logmin, const float* __restrict__ logmax,
    const float* __restrict__ scale, const float* __restrict__ bias,
    float* __restrict__ out) {
  constexpr int K = IN_DIM, N = OUT_DIM;
  constexpr int BK = 32;               // k-elems per tile
  constexpr int NIT = K / BK;          // 128 k-tiles

  __shared__ __align__(16) __bf16 sA[2][128 * BK];  // 2 x 8 KB
  __shared__ __align__(16) int    sS[2][64 * BK];   // 2 x 8 KB (chunk-XOR)
  __shared__ __align__(16) int    sG[2][64 * BK];   // 2 x 8 KB (chunk-XOR)

  const int tid  = threadIdx.x;
  const int lane = tid & 63;
  const int wave = tid >> 6;
  const int m16  = lane & 15;
  const int q    = lane >> 4;          // 0..3
  const int wn   = wave * 16;          // wave's N offset (1x4 layout)

  // XCD-grouped swizzle: 688 = 8 XCDs x 86; bm fastest so the 4 blocks
  // sharing a bn panel co-reside on one XCD (stored/sign reuse hits L2).
  const int wg  = blockIdx.x;                 // 0..687
  const int g   = (wg & 7) * 86 + (wg >> 3);  // bijective
  const int bm0 = (g & 3) * 128;              // 4 M-tiles
  const int bn0 = (g >> 2) * 64;              // 172 N-tiles

  const float lmin  = logmin[0];
  const float slope = (logmax[0] - lmin) * (1.0f / 254.0f);

  // ---- A staging (proven linear layout): row tid>>2, k-chunk (tid&3)*8 ----
  const int rA = tid >> 2;
  const __bf16* gA0 = A + (size_t)(bm0 + rA) * K + (tid & 3) * 8;
  const __bf16* gA1 = gA0 + (size_t)64 * K;

  // ---- B staging: lane-linear LDS, chunk-XOR'd GLOBAL source ----
  // LDS 16B-chunk c = instr*256 + tid maps to (row = c>>3, slot = c&7);
  // slot holds global k-chunk kc = slot ^ (row&7). row&7 is identical for
  // instr 0 (rows 0..31) and instr 1 (rows 32..63) at fixed tid.
  const int rB = tid >> 3;                    // 0..31 (instr0); +32 (instr1)
  const int kcB = (tid & 7) ^ (rB & 7);       // global k-chunk this lane loads
  const int* pS0 = stored + (size_t)(bn0 + rB) * K + kcB * 4;
  const int* pS1 = pS0 + (size_t)32 * K;
  const int* pG0 = sign + (size_t)(bn0 + rB) * K + kcB * 4;
  const int* pG1 = pG0 + (size_t)32 * K;

  // B read indices (int4 units): lane needs row wn+m16, k-chunks 2q, 2q+1.
  const int rowB = wn + m16;
  const int bIdx0 = rowB * 8 + ((2 * q) ^ (rowB & 7));      // chunk -> int4
  const int bIdx1 = rowB * 8 + ((2 * q + 1) ^ (rowB & 7));

  floatx4 acc[8] = {};

#define STAGE(KT, BUF)                                                        \
  {                                                                           \
    const int ke = (KT) * BK;                                                 \
    gl_lds16(gA0 + ke, &sA[BUF][tid * 8]);                                    \
    gl_lds16(gA1 + ke, &sA[BUF][2048 + tid * 8]);                             \
    gl_lds16(pS0 + ke, &sS[BUF][tid * 4]);                                    \
    gl_lds16(pS1 + ke, &sS[BUF][1024 + tid * 4]);                             \
    gl_lds16(pG0 + ke, &sG[BUF][tid * 4]);                                    \
    gl_lds16(pG1 + ke, &sG[BUF][1024 + tid * 4]);                             \
  }

  // Prologue: tile 0 -> buf 0; barrier drains vmcnt (compiler-inserted).
  STAGE(0, 0);
  __syncthreads();

  for (int t = 0; t < NIT; ++t) {
    const int c = t & 1;
    // Stage tile t+1 into buf c^1: its last readers finished before the
    // barrier we just passed; the barrier at the END of this iteration
    // drains vmcnt so it lands in time for iteration t+1.
    if (t + 1 < NIT) STAGE(t + 1, c ^ 1);

    bf16x8 afr[8];
#pragma unroll
    for (int mi = 0; mi < 8; ++mi)
      afr[mi] = *(const bf16x8*)&sA[c][(mi * 16 + m16) * BK + q * 8];
    const int4 bs0 = ((const int4*)sS[c])[bIdx0];
    const int4 bs1 = ((const int4*)sS[c])[bIdx1];
    const int4 bg0 = ((const int4*)sG[c])[bIdx0];
    const int4 bg1 = ((const int4*)sG[c])[bIdx1];

    const bf16x8 bfr = dec8(bs0, bs1, bg0, bg1, lmin, slope);

#pragma unroll
    for (int mi = 0; mi < 8; ++mi)
      acc[mi] = __builtin_amdgcn_mfma_f32_16x16x32_bf16(
          afr[mi], bfr, acc[mi], 0, 0, 0);

    __syncthreads();  // drains vmcnt (tile t+1 lands) + lgkm; one per tile
  }
#undef STAGE

  // Epilogue. C/D layout: col = lane&15, row = q*4 + reg  [m89]
  {
    const int col = bn0 + wn + m16;
    const float sc = scale[col];
    const float bb = bias[col] * sc;
#pragma unroll
    for (int mi = 0; mi < 8; ++mi) {
#pragma unroll
      for (int r = 0; r < 4; ++r) {
        const int row = bm0 + mi * 16 + q * 4 + r;
        out[row * N + col] = acc[mi][r] * sc + bb;
      }
    }
  }
}

// ---------------------------------------------------------------------------
extern "C" void kernel_launch(void* const* d_in, const int* in_sizes, int n_in,
                              void* d_out, int out_size, void* d_ws, size_t ws_size,
                              hipStream_t stream) {
  const float* x      = (const float*)d_in[0];
  const int*   stored = (const int*)d_in[1];
  const int*   sign   = (const int*)d_in[2];
  const float* logmin = (const float*)d_in[3];
  const float* logmax = (const float*)d_in[4];
  const float* scale  = (const float*)d_in[5];
  const float* bias   = (const float*)d_in[6];
  float* out = (float*)d_out;

  __bf16* wsX = (__bf16*)d_ws;  // 512*4096 bf16 = 4 MB

  conv_x_kernel<<<2048, 256, 0, stream>>>(x, wsX);
  // 172 bn-tiles x 4 bm-tiles = 688 blocks (XCD-swizzled)
  fused_qins_gemm_kernel<<<688, 256, 0, stream>>>(
      wsX, stored, sign, logmin, logmax, scale, bias, out);
}

// Round 9
// 468.815 us; speedup vs baseline: 1.9900x; 1.2446x over previous
//
#include <hip/hip_runtime.h>
#include <hip/hip_bf16.h>

// Problem constants
#define B_DIM   512
#define IN_DIM  4096
#define OUT_DIM 11008

typedef __bf16 bf16x4 __attribute__((ext_vector_type(4)));
typedef __bf16 bf16x8 __attribute__((ext_vector_type(8)));
typedef float  floatx4 __attribute__((ext_vector_type(4)));

// ---------------------------------------------------------------------------
// Pass 1: x fp32 -> bf16 (tiny: 12 MB traffic, ~2 us)
// ---------------------------------------------------------------------------
__global__ __launch_bounds__(256) void conv_x_kernel(
    const float* __restrict__ x, __bf16* __restrict__ xb) {
  int idx = blockIdx.x * blockDim.x + threadIdx.x;  // quad index
  float4 v = ((const float4*)x)[idx];
  bf16x4 o;
  o[0] = (__bf16)v.x; o[1] = (__bf16)v.y; o[2] = (__bf16)v.z; o[3] = (__bf16)v.w;
  ((bf16x4*)xb)[idx] = o;
}

// ---------------------------------------------------------------------------
// Pass 2: fused QINS-decode + GEMM, v7 (resubmit — round-8 bench was an
// infra failure: GPU acquisition timeout, kernel never ran).
// Cost model from v2(214)/v6(318): per-tile fixed cost (LDS bytes through a
// shared 128 B/cyc port + one vmcnt-drain) x 128 tiles dominates. Fix:
//  - BK=64 -> 64 tiles: halves barrier/drain events; body (~1500 cyc,
//    stretched by 3 resident blocks) >> HBM latency, so the compiler's
//    drain-at-barrier waits on loads issued a full body earlier (~free).
//  - v2's proven dataflow: B global->reg->decode->ds_write (coalesced,
//    compiler-managed waits); A via global_load_lds. ONE barrier/tile,
//    both sA and sB double-buffered. Zero inline asm.
//  - Floor-level LDS swizzle: slot = chunk ^ (row&7) on BOTH arrays
//    (sA: pre-swizzled gl_lds SOURCE per m173; sB: swizzled ds_write).
//    Hand-verified: every b128 access = 8 lanes per 16B quad = wave64 floor
//    (v2/v6 B-reads were 16-way -> 2x LDS time).
//  - 2x2 wave layout, acc 4x2; LDS/tile = 72 KB (1.1 B/k-row, 1.5x less
//    than v6); 48 KB LDS + launch_bounds(256,3) -> 3 blocks/CU.
// ---------------------------------------------------------------------------
__device__ __forceinline__ void gl_lds16(const void* g, void* l) {
  __builtin_amdgcn_global_load_lds(
      (const __attribute__((address_space(1))) void*)g,
      (__attribute__((address_space(3))) void*)l, 16, 0, 0);
}

// w = sign * exp(lmin + (255 - s)/254 * (lmax - lmin))
// sign as sign-bit XOR — verified bit-exact (v5/v6 passed).
__device__ __forceinline__ float dec1f(int s, int g, float lmin, float slope) {
  float e = __expf(fmaf((float)(255 - s), slope, lmin));
  return __uint_as_float(__float_as_uint(e) ^ ((unsigned)g & 0x80000000u));
}

__device__ __forceinline__ bf16x8 dec8(int4 sl, int4 sh, int4 gl, int4 gh,
                                       float lmin, float slope) {
  bf16x8 w;
  w[0] = (__bf16)dec1f(sl.x, gl.x, lmin, slope);
  w[1] = (__bf16)dec1f(sl.y, gl.y, lmin, slope);
  w[2] = (__bf16)dec1f(sl.z, gl.z, lmin, slope);
  w[3] = (__bf16)dec1f(sl.w, gl.w, lmin, slope);
  w[4] = (__bf16)dec1f(sh.x, gh.x, lmin, slope);
  w[5] = (__bf16)dec1f(sh.y, gh.y, lmin, slope);
  w[6] = (__bf16)dec1f(sh.z, gh.z, lmin, slope);
  w[7] = (__bf16)dec1f(sh.w, gh.w, lmin, slope);
  return w;
}

__global__ __launch_bounds__(256, 3) void fused_qins_gemm_kernel(
    const __bf16* __restrict__ A,      // 512 x 4096 bf16 (pre-converted x)
    const int* __restrict__ stored,    // 11008 x 4096 int32 in [1,255]
    const int* __restrict__ sign,      // 11008 x 4096 int32 +-1
    const float* __restrict__ logmin, const float* __restrict__ logmax,
    const float* __restrict__ scale, const float* __restrict__ bias,
    float* __restrict__ out) {
  constexpr int K = IN_DIM, N = OUT_DIM;
  constexpr int BK = 64;               // k-elems per tile
  constexpr int NT = K / BK;           // 64 k-tiles

  __shared__ __align__(16) __bf16 sA[2][128 * BK];  // 2 x 16 KB
  __shared__ __align__(16) __bf16 sB[2][64 * BK];   // 2 x 8 KB   (48 KB total)

  const int tid  = threadIdx.x;
  const int lane = tid & 63;
  const int wave = tid >> 6;
  const int wm   = (wave >> 1) * 64;   // wave M offset (0/64)
  const int wn   = (wave & 1) * 32;    // wave N offset (0/32)
  const int m16  = lane & 15;
  const int q    = lane >> 4;          // 0..3

  // XCD-grouped swizzle: 688 = 8 XCDs x 86; bm fastest so the 4 blocks
  // sharing a bn panel co-reside on one XCD (stored/sign reuse hits L2).
  const int wg  = blockIdx.x;                 // 0..687
  const int g   = (wg & 7) * 86 + (wg >> 3);  // bijective
  const int bm0 = (g & 3) * 128;              // 4 M-tiles
  const int bn0 = (g >> 2) * 64;              // 172 N-tiles

  const float lmin  = logmin[0];
  const float slope = (logmax[0] - lmin) * (1.0f / 254.0f);

  // ---- A staging: 4 gl_lds instrs, chunk-XOR on the GLOBAL source ----
  // LDS rows are 128 B (64 elems = 8 chunks of 8). Instr j, thread tid ->
  // LDS (row = j*32 + (tid>>3), slot = tid&7); slot holds global chunk
  // slot ^ (row&7). (row&7) invariant across j (j*32).
  const int arow = tid >> 3;                  // 0..31
  const int achk = (tid & 7) ^ (arow & 7);    // global k-chunk fetched
  const __bf16* gA = A + (size_t)(bm0 + arow) * K + achk * 8;
  // instr j source += j*32*K ; dest = sA[buf] + j*2048 + tid*8

  // ---- B staging: 16 ints/thread (row tid>>2, quarter tid&3) ----
  const int brow = tid >> 2;                  // 0..63
  const int bsub = tid & 3;                   // chunks 2*bsub, 2*bsub+1
  const int* pS = stored + (size_t)(bn0 + brow) * K + bsub * 16;
  const int* pG = sign   + (size_t)(bn0 + brow) * K + bsub * 16;
  const int wOff0 = brow * BK + (((2 * bsub)     ^ (brow & 7)) * 8);
  const int wOff1 = brow * BK + (((2 * bsub + 1) ^ (brow & 7)) * 8);

  // ---- frag read slots: chunk(kk) = 4*kk + q; row&7 = m16&7 for all mi/ni
  const int slotk0 = ((4 * 0 + q) ^ (m16 & 7)) * 8;
  const int slotk1 = ((4 * 1 + q) ^ (m16 & 7)) * 8;

  floatx4 acc[4][2] = {};

  // ---- Prologue: B(0) -> sB[0]; A(0) -> sA[0]; B(1) -> regs; barrier ----
  int4 s0, s1, s2, s3, g0, g1, g2, g3;
  s0 = *(const int4*)(pS);      s1 = *(const int4*)(pS + 4);
  s2 = *(const int4*)(pS + 8);  s3 = *(const int4*)(pS + 12);
  g0 = *(const int4*)(pG);      g1 = *(const int4*)(pG + 4);
  g2 = *(const int4*)(pG + 8);  g3 = *(const int4*)(pG + 12);
  *(bf16x8*)&sB[0][wOff0] = dec8(s0, s1, g0, g1, lmin, slope);
  *(bf16x8*)&sB[0][wOff1] = dec8(s2, s3, g2, g3, lmin, slope);
#pragma unroll
  for (int j = 0; j < 4; ++j)
    gl_lds16(gA + (size_t)j * 32 * K, &sA[0][j * 2048 + tid * 8]);
  s0 = *(const int4*)(pS + BK);      s1 = *(const int4*)(pS + BK + 4);
  s2 = *(const int4*)(pS + BK + 8);  s3 = *(const int4*)(pS + BK + 12);
  g0 = *(const int4*)(pG + BK);      g1 = *(const int4*)(pG + BK + 4);
  g2 = *(const int4*)(pG + BK + 8);  g3 = *(const int4*)(pG + BK + 12);
  __syncthreads();   // compiler drains vmcnt+lgkm: tile 0 fully resident

  // Body t (regs hold raw B(t+1) at entry; sA/sB[c] hold tile t):
  //   decode B(t+1) -> sB[c^1]; issue A(t+1) gl_lds -> sA[c^1];
  //   issue B(t+2) reg loads; ds_read frags(t); 16 MFMA; __syncthreads.
  // The end-of-body barrier drains loads issued at body START -> cover =
  // one full body (~1500 cyc x3 blocks) >> HBM latency.
  for (int t = 0; t < NT; ++t) {
    const int c = t & 1;

    *(bf16x8*)&sB[c ^ 1][wOff0] = dec8(s0, s1, g0, g1, lmin, slope);
    *(bf16x8*)&sB[c ^ 1][wOff1] = dec8(s2, s3, g2, g3, lmin, slope);

    const int ktA = ((t + 1 < NT) ? (t + 1) : 0) * BK;
#pragma unroll
    for (int j = 0; j < 4; ++j)
      gl_lds16(gA + (size_t)j * 32 * K + ktA, &sA[c ^ 1][j * 2048 + tid * 8]);

    const int ktB = ((t + 2 < NT) ? (t + 2) : 0) * BK;
    s0 = *(const int4*)(pS + ktB);      s1 = *(const int4*)(pS + ktB + 4);
    s2 = *(const int4*)(pS + ktB + 8);  s3 = *(const int4*)(pS + ktB + 12);
    g0 = *(const int4*)(pG + ktB);      g1 = *(const int4*)(pG + ktB + 4);
    g2 = *(const int4*)(pG + ktB + 8);  g3 = *(const int4*)(pG + ktB + 12);

    bf16x8 afr[4][2], bfr[2][2];
#pragma unroll
    for (int mi = 0; mi < 4; ++mi) {
      const int rbase = (wm + mi * 16 + m16) * BK;
      afr[mi][0] = *(const bf16x8*)&sA[c][rbase + slotk0];
      afr[mi][1] = *(const bf16x8*)&sA[c][rbase + slotk1];
    }
#pragma unroll
    for (int ni = 0; ni < 2; ++ni) {
      const int rbase = (wn + ni * 16 + m16) * BK;
      bfr[ni][0] = *(const bf16x8*)&sB[c][rbase + slotk0];
      bfr[ni][1] = *(const bf16x8*)&sB[c][rbase + slotk1];
    }

#pragma unroll
    for (int kk = 0; kk < 2; ++kk)
#pragma unroll
      for (int mi = 0; mi < 4; ++mi)
#pragma unroll
        for (int ni = 0; ni < 2; ++ni)
          acc[mi][ni] = __builtin_amdgcn_mfma_f32_16x16x32_bf16(
              afr[mi][kk], bfr[ni][kk], acc[mi][ni], 0, 0, 0);

    __syncthreads();
  }

  // Epilogue. C/D layout: col = lane&15, row = q*4 + reg  [m89]
#pragma unroll
  for (int ni = 0; ni < 2; ++ni) {
    const int col = bn0 + wn + ni * 16 + m16;
    const float sc = scale[col];
    const float bb = bias[col] * sc;
#pragma unroll
    for (int mi = 0; mi < 4; ++mi) {
#pragma unroll
      for (int r = 0; r < 4; ++r) {
        const int row = bm0 + wm + mi * 16 + q * 4 + r;
        out[row * N + col] = acc[mi][ni][r] * sc + bb;
      }
    }
  }
}

// ---------------------------------------------------------------------------
extern "C" void kernel_launch(void* const* d_in, const int* in_sizes, int n_in,
                              void* d_out, int out_size, void* d_ws, size_t ws_size,
                              hipStream_t stream) {
  const float* x      = (const float*)d_in[0];
  const int*   stored = (const int*)d_in[1];
  const int*   sign   = (const int*)d_in[2];
  const float* logmin = (const float*)d_in[3];
  const float* logmax = (const float*)d_in[4];
  const float* scale  = (const float*)d_in[5];
  const float* bias   = (const float*)d_in[6];
  float* out = (float*)d_out;

  __bf16* wsX = (__bf16*)d_ws;  // 512*4096 bf16 = 4 MB

  conv_x_kernel<<<2048, 256, 0, stream>>>(x, wsX);
  // 172 bn-tiles x 4 bm-tiles = 688 blocks (XCD-swizzled)
  fused_qins_gemm_kernel<<<688, 256, 0, stream>>>(
      wsX, stored, sign, logmin, logmax, scale, bias, out);
}